// Round 1
// baseline (155.814 us; speedup 1.0000x reference)
//
#include <hip/hip_runtime.h>
#include <math.h>

// Shapes from the reference
constexpr int NB = 1024;  // batch
constexpr int NT = 256;   // topic_size
constexpr int NE = 300;   // embedding_size

// M[t,f] = sum_e TE[e,t] * w_f[f,e]   (batch-independent "theta coefficient" matrix)
__global__ void k_M(const float* __restrict__ TE, const float* __restrict__ wf,
                    float* __restrict__ M) {
  __shared__ float te_col[NE];
  int t = blockIdx.x, f = threadIdx.x;
  for (int e = threadIdx.x; e < NE; e += blockDim.x) te_col[e] = TE[e * NT + t];
  __syncthreads();
  float acc = 0.f;
  const float* wrow = wf + f * NE;
  for (int e = 0; e < NE; ++e) acc = fmaf(te_col[e], wrow[e], acc);
  M[t * NT + f] = acc;
}

// G = M M^T (symmetric), u = M b_f
__global__ void k_G(const float* __restrict__ M, const float* __restrict__ bf,
                    float* __restrict__ G, float* __restrict__ u) {
  __shared__ float Mi[NT];
  __shared__ float red[NT];
  int i = blockIdx.x, j = threadIdx.x;
  Mi[j] = M[i * NT + j];
  __syncthreads();
  red[j] = Mi[j] * bf[j];
  __syncthreads();
  for (int s = NT / 2; s > 0; s >>= 1) {
    if (j < s) red[j] += red[j + s];
    __syncthreads();
  }
  if (j == 0) u[i] = red[0];
  float acc = 0.f;
  const float* Mj = M + j * NT;
  for (int k = 0; k < NT; ++k) acc = fmaf(Mi[k], Mj[k], acc);
  G[i * NT + j] = acc;
}

// One block per batch. eff[i,j] = r_i*w_j*G[i,j] + r_i*u_i  (softmax over i, per column j;
// terms constant in i dropped). Then S_i = sum_j softmax[i,j], and
// ave_req = (r/T)@M + b_f, ave_wsdl = ((S*r)/T)@M + b_f, out = cos * 3.
__global__ void k_main(const float* __restrict__ req, const float* __restrict__ wsdl,
                       const float* __restrict__ M, const float* __restrict__ G,
                       const float* __restrict__ u, const float* __restrict__ bf,
                       float* __restrict__ out) {
  __shared__ float r_s[NT], w_s[NT], ru_s[NT], m_s[NT], d_s[NT], q_s[NT];
  __shared__ float rn[4], ra[4], rb[4];
  int b = blockIdx.x, tid = threadIdx.x;
  float rt = req[b * NT + tid];
  r_s[tid] = rt;
  w_s[tid] = wsdl[b * NT + tid];
  ru_s[tid] = rt * u[tid];
  __syncthreads();

  // Phase A: per-column (j = tid) softmax max + denom. G[i*NT+j]: coalesced over j.
  {
    int j = tid;
    float wj = w_s[j];
    float m = -1e30f;
    for (int i = 0; i < NT; ++i) {
      float v = fmaf(r_s[i] * wj, G[i * NT + j], ru_s[i]);
      m = fmaxf(m, v);
    }
    float d = 0.f;
    for (int i = 0; i < NT; ++i) {
      float v = fmaf(r_s[i] * wj, G[i * NT + j], ru_s[i]);
      d += __expf(v - m);
    }
    m_s[j] = m;
    d_s[j] = 1.0f / d;
  }
  __syncthreads();

  // Phase S: per-row (i = tid) sums of softmaxed att. Uses G symmetry: G[i,j] = G[j*NT+i],
  // coalesced over i.
  {
    int i = tid;
    float ri = r_s[i], rui = ru_s[i];
    float S = 0.f;
    for (int j = 0; j < NT; ++j) {
      float v = fmaf(ri * w_s[j], G[j * NT + i], rui);
      S += __expf(v - m_s[j]) * d_s[j];
    }
    q_s[i] = S * ri;
  }
  __syncthreads();

  // Phase B: two fused matvecs against M (coalesced over k = tid), then cosine.
  float ar = 0.f, aw = 0.f;
  {
    int k = tid;
    for (int t = 0; t < NT; ++t) {
      float mk = M[t * NT + k];
      ar = fmaf(r_s[t], mk, ar);
      aw = fmaf(q_s[t], mk, aw);
    }
    float bk = bf[k];
    ar = ar * (1.0f / NT) + bk;
    aw = aw * (1.0f / NT) + bk;
  }
  float num = ar * aw, n1 = ar * ar, n2 = aw * aw;
  for (int off = 32; off > 0; off >>= 1) {
    num += __shfl_down(num, off, 64);
    n1  += __shfl_down(n1, off, 64);
    n2  += __shfl_down(n2, off, 64);
  }
  int wave = tid >> 6, lane = tid & 63;
  if (lane == 0) { rn[wave] = num; ra[wave] = n1; rb[wave] = n2; }
  __syncthreads();
  if (tid == 0) {
    float N = rn[0] + rn[1] + rn[2] + rn[3];
    float A = ra[0] + ra[1] + ra[2] + ra[3];
    float C = rb[0] + rb[1] + rb[2] + rb[3];
    float denom = fmaxf(sqrtf(A) * sqrtf(C), 1e-8f);
    out[b] = N / denom * 3.0f;
  }
}

extern "C" void kernel_launch(void* const* d_in, const int* in_sizes, int n_in,
                              void* d_out, int out_size, void* d_ws, size_t ws_size,
                              hipStream_t stream) {
  const float* req  = (const float*)d_in[0];
  const float* wsdl = (const float*)d_in[1];
  const float* TE   = (const float*)d_in[2];
  const float* wf   = (const float*)d_in[3];
  const float* bf   = (const float*)d_in[4];
  float* out = (float*)d_out;

  float* M = (float*)d_ws;          // 256*256 floats
  float* G = M + NT * NT;           // 256*256 floats
  float* u = G + NT * NT;           // 256 floats

  k_M<<<NT, NT, 0, stream>>>(TE, wf, M);
  k_G<<<NT, NT, 0, stream>>>(M, bf, G, u);
  k_main<<<NB, NT, 0, stream>>>(req, wsdl, M, G, u, bf, out);
}